// Round 4
// baseline (25.893 us; speedup 1.0000x reference)
//
#include <hip/hip_runtime.h>
#include <hip/hip_bf16.h>

// Embedding gather: out[t, :] = weight[tokens[t], :]
// tokens: [16384] int, weight: [32000, 1024] fp32, out: [16384, 1024] fp32.
//
// v3b: v2 structure (8 tokens/block, 8 outstanding 16B loads per lane)
// + NONTEMPORAL stores for the output stream (never re-read; keep L2 for
// the gathered weight rows). Uses clang ext_vector float4 because
// __builtin_nontemporal_store rejects HIP_vector_type.

#define DIM 1024
#define V4  (DIM / 4)        // 256 x 16B per row
#define TPB 8                // tokens per block

typedef float f32x4 __attribute__((ext_vector_type(4)));

__global__ __launch_bounds__(256) void embed_gather_kernel(
    const int* __restrict__ tokens,
    const f32x4* __restrict__ weight,    // [VOCAB][V4]
    f32x4* __restrict__ out,             // [NTOK][V4]
    int ntok)
{
    int base = blockIdx.x * TPB;
    int lane = threadIdx.x;

    int toks[TPB];
#pragma unroll
    for (int i = 0; i < TPB; ++i) {
        int t = base + i;
        toks[i] = (t < ntok) ? tokens[t] : 0;   // uniform (scalar) loads
    }

    f32x4 v[TPB];
#pragma unroll
    for (int i = 0; i < TPB; ++i) {
        v[i] = weight[(size_t)toks[i] * V4 + lane];   // 8 independent loads
    }

#pragma unroll
    for (int i = 0; i < TPB; ++i) {
        int t = base + i;
        if (t < ntok)
            __builtin_nontemporal_store(v[i], &out[(size_t)t * V4 + lane]);
    }
}

extern "C" void kernel_launch(void* const* d_in, const int* in_sizes, int n_in,
                              void* d_out, int out_size, void* d_ws, size_t ws_size,
                              hipStream_t stream) {
    const int*   tokens = (const int*)d_in[0];
    const float* weight = (const float*)d_in[1];
    float*       out    = (float*)d_out;

    int ntok = in_sizes[0];   // 8 * 2048 = 16384

    int nblk = (ntok + TPB - 1) / TPB;   // 2048
    embed_gather_kernel<<<dim3(nblk), dim3(256), 0, stream>>>(
        tokens, (const f32x4*)weight, (f32x4*)out, ntok);
}

// Round 5
// 25.122 us; speedup vs baseline: 1.0307x; 1.0307x over previous
//
#include <hip/hip_runtime.h>
#include <hip/hip_bf16.h>

// Embedding gather: out[t, :] = weight[tokens[t], :]
// tokens: [16384] int, weight: [32000, 1024] fp32, out: [16384, 1024] fp32.
//
// v4: ONE WAVE PER TOKEN. Each wave reads its whole 4 KiB row as 4
// back-to-back contiguous 1 KiB wave-requests (lane l takes float4s
// l, l+64, l+128, l+192), so the row's cachelines are issued by a single
// wave in address order — maximal page/channel locality per row. 4
// independent loads per lane; nontemporal stores for the write stream.
// 4096 blocks x 4 waves (4 tokens/block, one per wave).

#define DIM 1024
#define V4  (DIM / 4)        // 256 x 16B per row
#define WPB 4                // waves (= tokens) per block

typedef float f32x4 __attribute__((ext_vector_type(4)));

__global__ __launch_bounds__(256) void embed_gather_kernel(
    const int* __restrict__ tokens,
    const f32x4* __restrict__ weight,    // [VOCAB][V4]
    f32x4* __restrict__ out,             // [NTOK][V4]
    int ntok)
{
    int wave = threadIdx.x >> 6;         // 0..3
    int lane = threadIdx.x & 63;
    int t = blockIdx.x * WPB + wave;
    if (t >= ntok) return;

    int tok = tokens[t];                 // wave-uniform load
    const f32x4* src = weight + (size_t)tok * V4;
    f32x4* dst = out + (size_t)t * V4;

    // 4 contiguous 1 KiB wave-requests covering the 4 KiB row, all in flight
    f32x4 a = src[lane];
    f32x4 b = src[lane + 64];
    f32x4 c = src[lane + 128];
    f32x4 d = src[lane + 192];

    __builtin_nontemporal_store(a, &dst[lane]);
    __builtin_nontemporal_store(b, &dst[lane + 64]);
    __builtin_nontemporal_store(c, &dst[lane + 128]);
    __builtin_nontemporal_store(d, &dst[lane + 192]);
}

extern "C" void kernel_launch(void* const* d_in, const int* in_sizes, int n_in,
                              void* d_out, int out_size, void* d_ws, size_t ws_size,
                              hipStream_t stream) {
    const int*   tokens = (const int*)d_in[0];
    const float* weight = (const float*)d_in[1];
    float*       out    = (float*)d_out;

    int ntok = in_sizes[0];   // 8 * 2048 = 16384

    int nblk = (ntok + WPB - 1) / WPB;   // 4096
    embed_gather_kernel<<<dim3(nblk), dim3(256), 0, stream>>>(
        tokens, (const f32x4*)weight, (f32x4*)out, ntok);
}